// Round 1
// 2066.145 us; speedup vs baseline: 1.1408x; 1.1408x over previous
//
#include <hip/hip_runtime.h>

// ---------------- model constants ----------------
#define DM    1024      // D_MODEL
#define DI    2048      // D_INNER
#define DS    16        // D_STATE
#define DTR   64        // DT_RANK
#define DCONV 4
#define NLAY  2
#define NVOCAB 50280
#define SEQ   1024
#define REPS  1e-5f

typedef unsigned short u16;
typedef short bf16x8 __attribute__((ext_vector_type(8)));
typedef float f32x4 __attribute__((ext_vector_type(4)));

__device__ __forceinline__ u16 bf16_rn(float f) {
  unsigned int u = __float_as_uint(f);
  return (u16)((u + 0x7fffu + ((u >> 16) & 1u)) >> 16);
}
__device__ __forceinline__ float bf16_to_f(u16 h) {
  return __uint_as_float((unsigned int)h << 16);
}
__device__ __forceinline__ float silu_f(float x) { return x / (1.f + __expf(-x)); }

// ---------------- embedding gather ----------------
__global__ void k_embed(const int* __restrict__ ids, const float* __restrict__ E,
                        float* __restrict__ x) {
  int t = blockIdx.x;
  int c = threadIdx.x * 4;
  float4 v = *(const float4*)&E[(size_t)ids[t] * DM + c];
  *(float4*)&x[(size_t)t * DM + c] = v;
}

// ---------------- rmsnorm -> bf16 hi + lo ----------------
__global__ void k_rmsnorm(const float* __restrict__ x, const float* __restrict__ sc,
                          u16* __restrict__ hi, u16* __restrict__ lo) {
  int t = blockIdx.x, tid = threadIdx.x;
  float4 v = *(const float4*)&x[(size_t)t * DM + tid * 4];
  float s = v.x * v.x + v.y * v.y + v.z * v.z + v.w * v.w;
  for (int o = 32; o; o >>= 1) s += __shfl_xor(s, o);
  __shared__ float red[4];
  if ((tid & 63) == 0) red[tid >> 6] = s;
  __syncthreads();
  float tot = red[0] + red[1] + red[2] + red[3];
  float r = rsqrtf(tot / (float)DM + REPS);
  int c = tid * 4;
  float f[4] = {v.x * r * sc[c + 0], v.y * r * sc[c + 1],
                v.z * r * sc[c + 2], v.w * r * sc[c + 3]};
  unsigned long long ph = 0, pl = 0;
#pragma unroll
  for (int i = 0; i < 4; i++) {
    u16 h = bf16_rn(f[i]);
    u16 l = bf16_rn(f[i] - bf16_to_f(h));
    ph |= (unsigned long long)h << (16 * i);
    pl |= (unsigned long long)l << (16 * i);
  }
  *(unsigned long long*)&hi[(size_t)t * DM + c] = ph;
  *(unsigned long long*)&lo[(size_t)t * DM + c] = pl;
}

// ---------------- fused weight transpose fp32(R,C) -> bf16 hi/lo (C,R) ----------------
struct TDesc { const float* src; u16* dhi; u16* dlo; int R, C, tstart; };
struct TPack { TDesc d[4]; };

__global__ void k_transpose(TPack p) {
  __shared__ float tile[32][33];
  int bt = blockIdx.x;
  int di = 0;
#pragma unroll
  for (int i = 1; i < 4; i++) if (bt >= p.d[i].tstart) di = i;
  TDesc d = p.d[di];
  int tloc = bt - d.tstart;
  int tpc = d.C >> 5;
  int r0 = (tloc / tpc) * 32, c0 = (tloc % tpc) * 32;
  int tx = threadIdx.x & 31, ty = threadIdx.x >> 5;
#pragma unroll
  for (int i = 0; i < 4; i++) {
    int r = ty + i * 8;
    tile[r][tx] = d.src[(size_t)(r0 + r) * d.C + c0 + tx];
  }
  __syncthreads();
#pragma unroll
  for (int i = 0; i < 4; i++) {
    int cr = ty + i * 8;
    float v = tile[tx][cr];
    u16 h = bf16_rn(v);
    size_t off = (size_t)(c0 + cr) * d.R + r0 + tx;
    d.dhi[off] = h;
    d.dlo[off] = bf16_rn(v - bf16_to_f(h));
  }
}

// ---------------- depthwise causal conv + silu (fp32 out) ----------------
__global__ void k_conv(const float* __restrict__ xr, const float* __restrict__ cw,
                       const float* __restrict__ cb, float* __restrict__ xc) {
  int i = blockIdx.x * 256 + threadIdx.x;   // t*DI + d
  int t = i >> 11, d = i & (DI - 1);
  float acc = cb[d];
#pragma unroll
  for (int k = 0; k < DCONV; k++) {
    int tt = t - (DCONV - 1) + k;
    if (tt >= 0) acc = fmaf(cw[k * DI + d], xr[(size_t)tt * (2 * DI) + d], acc);
  }
  xc[i] = silu_f(acc);
}

// ---------------- x_dbl = xc @ x_proj_w  (fp32, 96 outputs, pad-128 buffer) ----------------
__global__ void k_xdbl(const float* __restrict__ xc, const float* __restrict__ W,
                       float* __restrict__ xdbl) {
  __shared__ float rows[4][DI];
  int t0 = blockIdx.x * 4, tid = threadIdx.x;
#pragma unroll
  for (int it = 0; it < 16; it++) {
    int idx = it * 128 + tid;            // 2048 float4 total
    int r = idx >> 9, c = (idx & 511) * 4;
    *(float4*)&rows[r][c] = *(const float4*)&xc[(size_t)(t0 + r) * DI + c];
  }
  __syncthreads();
  int j = tid;
  if (j >= 96) return;
  float acc0 = 0.f, acc1 = 0.f, acc2 = 0.f, acc3 = 0.f;
#pragma unroll 4
  for (int k = 0; k < DI; k++) {
    float w = W[(size_t)k * 96 + j];
    acc0 = fmaf(rows[0][k], w, acc0);
    acc1 = fmaf(rows[1][k], w, acc1);
    acc2 = fmaf(rows[2][k], w, acc2);
    acc3 = fmaf(rows[3][k], w, acc3);
  }
  xdbl[(size_t)(t0 + 0) * 128 + j] = acc0;
  xdbl[(size_t)(t0 + 1) * 128 + j] = acc1;
  xdbl[(size_t)(t0 + 2) * 128 + j] = acc2;
  xdbl[(size_t)(t0 + 3) * 128 + j] = acc3;
}

// ---------------- delta = softplus(dt @ dt_proj_w + b)  (fp32) ----------------
__global__ void k_dtproj(const float* __restrict__ xdbl, const float* __restrict__ W,
                         const float* __restrict__ b, float* __restrict__ delta) {
  __shared__ float dt[4][DTR];
  int t0 = blockIdx.x * 4;
  int d = blockIdx.y * 256 + threadIdx.x;
  int tid = threadIdx.x;
  {
    int r = tid >> 6, k = tid & 63;
    dt[r][k] = xdbl[(size_t)(t0 + r) * 128 + k];
  }
  __syncthreads();
  float bias = b[d];
  float acc0 = bias, acc1 = bias, acc2 = bias, acc3 = bias;
#pragma unroll
  for (int k = 0; k < DTR; k++) {
    float w = W[(size_t)k * DI + d];
    acc0 = fmaf(dt[0][k], w, acc0);
    acc1 = fmaf(dt[1][k], w, acc1);
    acc2 = fmaf(dt[2][k], w, acc2);
    acc3 = fmaf(dt[3][k], w, acc3);
  }
  float a[4] = {acc0, acc1, acc2, acc3};
#pragma unroll
  for (int r = 0; r < 4; r++) {
    float v = a[r];
    delta[(size_t)(t0 + r) * DI + d] = (v > 20.f) ? v : log1pf(__expf(v));
  }
}

// ---------------- selective scan (sequential over t) ----------------
__global__ void k_scan(const float* __restrict__ delta, const float* __restrict__ xdbl,
                       const float* __restrict__ u, const float* __restrict__ A_log,
                       const float* __restrict__ Dskip, float* __restrict__ y) {
  int n = threadIdx.x & 15, dl = threadIdx.x >> 4;
  int d = blockIdx.x * 16 + dl;
  float An = -__expf(A_log[d * DS + n]);
  float Dd = Dskip[d];
  float h = 0.f;
  float del = delta[d], uu = u[d];
  float Bn = xdbl[64 + n], Cn = xdbl[80 + n];
  for (int t = 0; t < SEQ; t++) {
    float del2 = 0.f, uu2 = 0.f, Bn2 = 0.f, Cn2 = 0.f;
    if (t + 1 < SEQ) {          // prefetch next step (keeps dep chain = exp+fma)
      del2 = delta[(size_t)(t + 1) * DI + d];
      uu2 = u[(size_t)(t + 1) * DI + d];
      Bn2 = xdbl[(t + 1) * 128 + 64 + n];
      Cn2 = xdbl[(t + 1) * 128 + 80 + n];
    }
    float dA = __expf(del * An);
    h = fmaf(dA, h, del * Bn * uu);
    float p = h * Cn;
    p += __shfl_xor(p, 8);
    p += __shfl_xor(p, 4);
    p += __shfl_xor(p, 2);
    p += __shfl_xor(p, 1);
    if (n == 0) y[(size_t)t * DI + d] = fmaf(uu, Dd, p);
    del = del2; uu = uu2; Bn = Bn2; Cn = Cn2;
  }
}

// ---------------- y2 = y * silu(res) -> bf16 hi + lo ----------------
__global__ void k_y2(const float* __restrict__ y, const float* __restrict__ xr,
                     u16* __restrict__ hi, u16* __restrict__ lo) {
  int i = blockIdx.x * 256 + threadIdx.x;
  int t = i >> 11, d = i & (DI - 1);
  float r = xr[(size_t)t * (2 * DI) + DI + d];
  float v = y[i] * silu_f(r);
  u16 h = bf16_rn(v);
  hi[i] = h;
  lo[i] = bf16_rn(v - bf16_to_f(h));
}

// ---------------- MFMA GEMM: C(M,N) = A(M,K)bf16 @ Bt(N,K) ----------------
#define EPI_STORE 0
#define EPI_ADD 1

__device__ __forceinline__ void async16(const u16* g, u16* l) {
  __builtin_amdgcn_global_load_lds(
      (const __attribute__((address_space(1))) unsigned int*)g,
      (__attribute__((address_space(3))) unsigned int*)l, 16, 0, 0);
}

// XCD-aware bijective swizzle (all grids here are multiples of 8):
// consecutive work items (m fastest) land on the SAME XCD so the 8 m-blocks
// sharing a B n-tile hit that XCD's L2 instead of 8 different L2s.
__device__ __forceinline__ int xcd_swz(int bx, int nwg) {
  return (bx & 7) * (nwg >> 3) + (bx >> 3);
}

template <int EPI, bool BF32, bool NGUARD>
__launch_bounds__(256)
__global__ void k_gemm(const u16* __restrict__ A, const void* __restrict__ Bt,
                       float* __restrict__ C, int M, int N, int K,
                       int ldA, int ldB, int ldC, int Mb) {
  __shared__ u16 lds_a[128 * 32];
  __shared__ u16 lds_b[128 * 32];
  int bx = xcd_swz(blockIdx.x, gridDim.x);
  int m0 = (bx % Mb) * 128;
  int n0 = (bx / Mb) * 128;
  int tid = threadIdx.x, ln = tid & 63;
  int wv = tid >> 6, wm = wv >> 1, wn = wv & 1;
  int ml = ln & 15, q = ln >> 4;

  f32x4 zero = {0.f, 0.f, 0.f, 0.f};
  f32x4 acc[4][4];
#pragma unroll
  for (int i = 0; i < 4; i++)
#pragma unroll
    for (int j = 0; j < 4; j++) acc[i][j] = zero;

  for (int k0 = 0; k0 < K; k0 += 32) {
    __syncthreads();
#pragma unroll
    for (int r = 0; r < 2; r++) {
      int idx = r * 256 + tid;
      const u16* g = A + (size_t)(m0 + (idx >> 2)) * ldA + k0 + (idx & 3) * 8;
      u16* l = lds_a + (size_t)(r * 256 + (tid & ~63)) * 8;
      async16(g, l);
    }
    if (!BF32) {
#pragma unroll
      for (int r = 0; r < 2; r++) {
        int idx = r * 256 + tid;
        const u16* g = (const u16*)Bt + (size_t)(n0 + (idx >> 2)) * ldB + k0 + (idx & 3) * 8;
        u16* l = lds_b + (size_t)(r * 256 + (tid & ~63)) * 8;
        async16(g, l);
      }
    } else {
      // B source fp32 (N,K): read float4, convert to bf16, ds_write
#pragma unroll
      for (int r = 0; r < 4; r++) {
        int idx = r * 256 + tid;
        int row = idx >> 3, cg = idx & 7;
        int nr = n0 + row;
        if (NGUARD) nr = min(nr, N - 1);
        float4 v = *(const float4*)((const float*)Bt + (size_t)nr * ldB + k0 + cg * 4);
        unsigned long long pk =
            (unsigned long long)bf16_rn(v.x) |
            ((unsigned long long)bf16_rn(v.y) << 16) |
            ((unsigned long long)bf16_rn(v.z) << 32) |
            ((unsigned long long)bf16_rn(v.w) << 48);
        *(unsigned long long*)&lds_b[row * 32 + cg * 4] = pk;
      }
    }
    __syncthreads();

    bf16x8 af[4], bfr[4];
#pragma unroll
    for (int i = 0; i < 4; i++)
      af[i] = *(const bf16x8*)&lds_a[(wm * 64 + i * 16 + ml) * 32 + q * 8];
#pragma unroll
    for (int j = 0; j < 4; j++)
      bfr[j] = *(const bf16x8*)&lds_b[(wn * 64 + j * 16 + ml) * 32 + q * 8];
#pragma unroll
    for (int i = 0; i < 4; i++)
#pragma unroll
      for (int j = 0; j < 4; j++)
        acc[i][j] = __builtin_amdgcn_mfma_f32_16x16x32_bf16(af[i], bfr[j], acc[i][j], 0, 0, 0);
  }

  // C/D layout: col=lane&15, row=(lane>>4)*4+reg  [verified m89/m91]
#pragma unroll
  for (int i = 0; i < 4; i++)
#pragma unroll
    for (int j = 0; j < 4; j++) {
      int c = n0 + wn * 64 + j * 16 + ml;
      if (NGUARD && c >= N) continue;
      int rbase = m0 + wm * 64 + i * 16 + q * 4;
#pragma unroll
      for (int rg = 0; rg < 4; rg++) {
        int r = rbase + rg;
        float v = acc[i][j][rg];
        size_t off = (size_t)r * ldC + c;
        if (EPI == EPI_STORE) C[off] = v;
        else C[off] += v;
      }
    }
}

// ---------------- fused split-bf16 GEMM: C = Ah@Bh + Al@Bh + Ah@Bl ----------------
// Replaces 3 k_gemm launches: one staging pass, one C write (no fp32 RMW x2).
template <int EPI>
__launch_bounds__(256)
__global__ void k_gemm3(const u16* __restrict__ Ah, const u16* __restrict__ Al,
                        const u16* __restrict__ Bh, const u16* __restrict__ Bl,
                        float* __restrict__ C, int M, int N, int K,
                        int ldA, int ldB, int ldC, int Mb) {
  __shared__ u16 lds_ah[128 * 32];
  __shared__ u16 lds_al[128 * 32];
  __shared__ u16 lds_bh[128 * 32];
  __shared__ u16 lds_bl[128 * 32];
  int bx = xcd_swz(blockIdx.x, gridDim.x);
  int m0 = (bx % Mb) * 128;
  int n0 = (bx / Mb) * 128;
  int tid = threadIdx.x, ln = tid & 63;
  int wv = tid >> 6, wm = wv >> 1, wn = wv & 1;
  int ml = ln & 15, q = ln >> 4;

  f32x4 zero = {0.f, 0.f, 0.f, 0.f};
  f32x4 acc[4][4];
#pragma unroll
  for (int i = 0; i < 4; i++)
#pragma unroll
    for (int j = 0; j < 4; j++) acc[i][j] = zero;

  for (int k0 = 0; k0 < K; k0 += 32) {
    __syncthreads();
#pragma unroll
    for (int r = 0; r < 2; r++) {
      int idx = r * 256 + tid;
      size_t goffA = (size_t)(m0 + (idx >> 2)) * ldA + k0 + (idx & 3) * 8;
      size_t goffB = (size_t)(n0 + (idx >> 2)) * ldB + k0 + (idx & 3) * 8;
      size_t loff = (size_t)(r * 256 + (tid & ~63)) * 8;
      async16(Ah + goffA, lds_ah + loff);
      async16(Al + goffA, lds_al + loff);
      async16(Bh + goffB, lds_bh + loff);
      async16(Bl + goffB, lds_bl + loff);
    }
    __syncthreads();

    bf16x8 ah[4], al[4], bh[4], bl[4];
#pragma unroll
    for (int i = 0; i < 4; i++) {
      int ro = (wm * 64 + i * 16 + ml) * 32 + q * 8;
      ah[i] = *(const bf16x8*)&lds_ah[ro];
      al[i] = *(const bf16x8*)&lds_al[ro];
    }
#pragma unroll
    for (int j = 0; j < 4; j++) {
      int ro = (wn * 64 + j * 16 + ml) * 32 + q * 8;
      bh[j] = *(const bf16x8*)&lds_bh[ro];
      bl[j] = *(const bf16x8*)&lds_bl[ro];
    }
#pragma unroll
    for (int i = 0; i < 4; i++)
#pragma unroll
      for (int j = 0; j < 4; j++) {
        acc[i][j] = __builtin_amdgcn_mfma_f32_16x16x32_bf16(ah[i], bh[j], acc[i][j], 0, 0, 0);
        acc[i][j] = __builtin_amdgcn_mfma_f32_16x16x32_bf16(al[i], bh[j], acc[i][j], 0, 0, 0);
        acc[i][j] = __builtin_amdgcn_mfma_f32_16x16x32_bf16(ah[i], bl[j], acc[i][j], 0, 0, 0);
      }
  }

#pragma unroll
  for (int i = 0; i < 4; i++)
#pragma unroll
    for (int j = 0; j < 4; j++) {
      int c = n0 + wn * 64 + j * 16 + ml;
      int rbase = m0 + wm * 64 + i * 16 + q * 4;
#pragma unroll
      for (int rg = 0; rg < 4; rg++) {
        int r = rbase + rg;
        float v = acc[i][j][rg];
        size_t off = (size_t)r * ldC + c;
        if (EPI == EPI_STORE) C[off] = v;
        else C[off] += v;
      }
    }
}

// ---------------- host side ----------------
extern "C" void kernel_launch(void* const* d_in, const int* in_sizes, int n_in,
                              void* d_out, int out_size, void* d_ws, size_t ws_size,
                              hipStream_t stream) {
  const int* ids = (const int*)d_in[0];
  const float* E = (const float*)d_in[1];
  const float* norm_scale = (const float*)d_in[2];
  const float* in_proj_w = (const float*)d_in[3];
  const float* conv_w = (const float*)d_in[4];
  const float* conv_b = (const float*)d_in[5];
  const float* x_proj_w = (const float*)d_in[6];
  const float* dt_proj_w = (const float*)d_in[7];
  const float* dt_proj_b = (const float*)d_in[8];
  const float* A_log = (const float*)d_in[9];
  const float* D_skip = (const float*)d_in[10];
  const float* out_proj_w = (const float*)d_in[11];
  const float* norm_f_scale = (const float*)d_in[12];
  float* out = (float*)d_out;

  char* p = (char*)d_ws;
  auto alloc = [&](size_t bytes) { char* r = p; p += (bytes + 255) & ~(size_t)255; return r; };
  float* x = (float*)alloc((size_t)SEQ * DM * 4);
  u16* xn_h = (u16*)alloc((size_t)SEQ * DM * 2);
  u16* xn_l = (u16*)alloc((size_t)SEQ * DM * 2);
  float* xr = (float*)alloc((size_t)SEQ * 2 * DI * 4);
  float* xc = (float*)alloc((size_t)SEQ * DI * 4);
  float* xdbl = (float*)alloc((size_t)SEQ * 128 * 4);
  float* delta = (float*)alloc((size_t)SEQ * DI * 4);
  float* ybuf = (float*)alloc((size_t)SEQ * DI * 4);
  u16* y2h = (u16*)alloc((size_t)SEQ * DI * 2);
  u16* y2l = (u16*)alloc((size_t)SEQ * DI * 2);
  u16* xf_h = (u16*)alloc((size_t)SEQ * DM * 2);
  u16* xf_l = (u16*)alloc((size_t)SEQ * DM * 2);
  u16 *inTh[NLAY], *inTl[NLAY], *outTh[NLAY], *outTl[NLAY];
  for (int l = 0; l < NLAY; l++) {
    inTh[l] = (u16*)alloc((size_t)(2 * DI) * DM * 2);
    inTl[l] = (u16*)alloc((size_t)(2 * DI) * DM * 2);
    outTh[l] = (u16*)alloc((size_t)DM * DI * 2);
    outTl[l] = (u16*)alloc((size_t)DM * DI * 2);
  }

  // weight transposes fp32(R,C) -> bf16 hi/lo (C,R)
  TPack pk;
  int ts = 0;
  for (int l = 0; l < NLAY; l++) {
    pk.d[l * 2 + 0] = {in_proj_w + (size_t)l * DM * 2 * DI, inTh[l], inTl[l], DM, 2 * DI, ts};
    ts += (DM / 32) * (2 * DI / 32);      // 4096
    pk.d[l * 2 + 1] = {out_proj_w + (size_t)l * DI * DM, outTh[l], outTl[l], DI, DM, ts};
    ts += (DI / 32) * (DM / 32);          // 2048
  }
  k_transpose<<<ts, 256, 0, stream>>>(pk);

  k_embed<<<SEQ, 256, 0, stream>>>(ids, E, x);

  for (int l = 0; l < NLAY; l++) {
    k_rmsnorm<<<SEQ, 256, 0, stream>>>(x, norm_scale + (size_t)l * DM, xn_h, xn_l);
    // xr = Ah*Wh + Al*Wh + Ah*Wl (split-bf16, near-fp32) — single fused pass
    k_gemm3<EPI_STORE><<<8 * 32, 256, 0, stream>>>(
        xn_h, xn_l, inTh[l], inTl[l], xr, SEQ, 2 * DI, DM, DM, DM, 2 * DI, 8);
    k_conv<<<(SEQ * DI) / 256, 256, 0, stream>>>(
        xr, conv_w + (size_t)l * DCONV * DI, conv_b + (size_t)l * DI, xc);
    k_xdbl<<<SEQ / 4, 128, 0, stream>>>(xc, x_proj_w + (size_t)l * DI * 96, xdbl);
    {
      dim3 g(SEQ / 4, DI / 256);
      k_dtproj<<<g, 256, 0, stream>>>(xdbl, dt_proj_w + (size_t)l * DTR * DI,
                                      dt_proj_b + (size_t)l * DI, delta);
    }
    k_scan<<<DI / 16, 256, 0, stream>>>(delta, xdbl, xc,
                                        A_log + (size_t)l * DI * DS,
                                        D_skip + (size_t)l * DI, ybuf);
    k_y2<<<(SEQ * DI) / 256, 256, 0, stream>>>(ybuf, xr, y2h, y2l);
    // x += y2h*Wh + y2l*Wh + y2h*Wl — single fused pass
    k_gemm3<EPI_ADD><<<8 * 8, 256, 0, stream>>>(
        y2h, y2l, outTh[l], outTl[l], x, SEQ, DM, DI, DI, DI, DM, 8);
  }

  k_rmsnorm<<<SEQ, 256, 0, stream>>>(x, norm_f_scale, xf_h, xf_l);
  // logits = xf @ E^T (E read fp32, converted in staging; single-bf16 is in budget)
  int nblk = (NVOCAB + 127) / 128;  // 393
  k_gemm<EPI_STORE, true, true><<<8 * nblk, 256, 0, stream>>>(
      xf_h, E, out, SEQ, NVOCAB, DM, DM, DM, NVOCAB, 8);
}

// Round 2
// 1905.998 us; speedup vs baseline: 1.2366x; 1.0840x over previous
//
#include <hip/hip_runtime.h>

// ---------------- model constants ----------------
#define DM    1024      // D_MODEL
#define DI    2048      // D_INNER
#define DS    16        // D_STATE
#define DTR   64        // DT_RANK
#define DCONV 4
#define NLAY  2
#define NVOCAB 50280
#define SEQ   1024
#define REPS  1e-5f

typedef unsigned short u16;
typedef short bf16x8 __attribute__((ext_vector_type(8)));
typedef float f32x4 __attribute__((ext_vector_type(4)));

__device__ __forceinline__ u16 bf16_rn(float f) {
  unsigned int u = __float_as_uint(f);
  return (u16)((u + 0x7fffu + ((u >> 16) & 1u)) >> 16);
}
__device__ __forceinline__ float bf16_to_f(u16 h) {
  return __uint_as_float((unsigned int)h << 16);
}
__device__ __forceinline__ float silu_f(float x) { return x / (1.f + __expf(-x)); }

// ---------------- embedding gather ----------------
__global__ void k_embed(const int* __restrict__ ids, const float* __restrict__ E,
                        float* __restrict__ x) {
  int t = blockIdx.x;
  int c = threadIdx.x * 4;
  float4 v = *(const float4*)&E[(size_t)ids[t] * DM + c];
  *(float4*)&x[(size_t)t * DM + c] = v;
}

// ---------------- E fp32 -> bf16 (one-time, removes per-K-step convert in logits GEMM) ----
__global__ void k_e2bf(const float* __restrict__ E, u16* __restrict__ Eb) {
  size_t i = ((size_t)blockIdx.x * 256 + threadIdx.x) * 8;
  float4 a = *(const float4*)&E[i];
  float4 b = *(const float4*)&E[i + 4];
  union { u16 s[8]; float4 v; } o;
  o.s[0] = bf16_rn(a.x); o.s[1] = bf16_rn(a.y);
  o.s[2] = bf16_rn(a.z); o.s[3] = bf16_rn(a.w);
  o.s[4] = bf16_rn(b.x); o.s[5] = bf16_rn(b.y);
  o.s[6] = bf16_rn(b.z); o.s[7] = bf16_rn(b.w);
  *(float4*)&Eb[i] = o.v;
}

// ---------------- rmsnorm -> bf16 hi + lo ----------------
__global__ void k_rmsnorm(const float* __restrict__ x, const float* __restrict__ sc,
                          u16* __restrict__ hi, u16* __restrict__ lo) {
  int t = blockIdx.x, tid = threadIdx.x;
  float4 v = *(const float4*)&x[(size_t)t * DM + tid * 4];
  float s = v.x * v.x + v.y * v.y + v.z * v.z + v.w * v.w;
  for (int o = 32; o; o >>= 1) s += __shfl_xor(s, o);
  __shared__ float red[4];
  if ((tid & 63) == 0) red[tid >> 6] = s;
  __syncthreads();
  float tot = red[0] + red[1] + red[2] + red[3];
  float r = rsqrtf(tot / (float)DM + REPS);
  int c = tid * 4;
  float f[4] = {v.x * r * sc[c + 0], v.y * r * sc[c + 1],
                v.z * r * sc[c + 2], v.w * r * sc[c + 3]};
  unsigned long long ph = 0, pl = 0;
#pragma unroll
  for (int i = 0; i < 4; i++) {
    u16 h = bf16_rn(f[i]);
    u16 l = bf16_rn(f[i] - bf16_to_f(h));
    ph |= (unsigned long long)h << (16 * i);
    pl |= (unsigned long long)l << (16 * i);
  }
  *(unsigned long long*)&hi[(size_t)t * DM + c] = ph;
  *(unsigned long long*)&lo[(size_t)t * DM + c] = pl;
}

// ---------------- fused weight transpose fp32(R,C) -> bf16 hi/lo (C,R) ----------------
struct TDesc { const float* src; u16* dhi; u16* dlo; int R, C, tstart; };
struct TPack { TDesc d[4]; };

__global__ void k_transpose(TPack p) {
  __shared__ float tile[32][33];
  int bt = blockIdx.x;
  int di = 0;
#pragma unroll
  for (int i = 1; i < 4; i++) if (bt >= p.d[i].tstart) di = i;
  TDesc d = p.d[di];
  int tloc = bt - d.tstart;
  int tpc = d.C >> 5;
  int r0 = (tloc / tpc) * 32, c0 = (tloc % tpc) * 32;
  int tx = threadIdx.x & 31, ty = threadIdx.x >> 5;
#pragma unroll
  for (int i = 0; i < 4; i++) {
    int r = ty + i * 8;
    tile[r][tx] = d.src[(size_t)(r0 + r) * d.C + c0 + tx];
  }
  __syncthreads();
#pragma unroll
  for (int i = 0; i < 4; i++) {
    int cr = ty + i * 8;
    float v = tile[tx][cr];
    u16 h = bf16_rn(v);
    size_t off = (size_t)(c0 + cr) * d.R + r0 + tx;
    d.dhi[off] = h;
    d.dlo[off] = bf16_rn(v - bf16_to_f(h));
  }
}

// ---------------- depthwise causal conv + silu (fp32 out) ----------------
__global__ void k_conv(const float* __restrict__ xr, const float* __restrict__ cw,
                       const float* __restrict__ cb, float* __restrict__ xc) {
  int i = blockIdx.x * 256 + threadIdx.x;   // t*DI + d
  int t = i >> 11, d = i & (DI - 1);
  float acc = cb[d];
#pragma unroll
  for (int k = 0; k < DCONV; k++) {
    int tt = t - (DCONV - 1) + k;
    if (tt >= 0) acc = fmaf(cw[k * DI + d], xr[(size_t)tt * (2 * DI) + d], acc);
  }
  xc[i] = silu_f(acc);
}

// ---------------- x_dbl = xc @ x_proj_w  (fp32, 96 outputs, pad-128 buffer) ----------------
__global__ void k_xdbl(const float* __restrict__ xc, const float* __restrict__ W,
                       float* __restrict__ xdbl) {
  __shared__ float rows[4][DI];
  int t0 = blockIdx.x * 4, tid = threadIdx.x;
#pragma unroll
  for (int it = 0; it < 16; it++) {
    int idx = it * 128 + tid;            // 2048 float4 total
    int r = idx >> 9, c = (idx & 511) * 4;
    *(float4*)&rows[r][c] = *(const float4*)&xc[(size_t)(t0 + r) * DI + c];
  }
  __syncthreads();
  int j = tid;
  if (j >= 96) return;
  float acc0 = 0.f, acc1 = 0.f, acc2 = 0.f, acc3 = 0.f;
#pragma unroll 4
  for (int k = 0; k < DI; k++) {
    float w = W[(size_t)k * 96 + j];
    acc0 = fmaf(rows[0][k], w, acc0);
    acc1 = fmaf(rows[1][k], w, acc1);
    acc2 = fmaf(rows[2][k], w, acc2);
    acc3 = fmaf(rows[3][k], w, acc3);
  }
  xdbl[(size_t)(t0 + 0) * 128 + j] = acc0;
  xdbl[(size_t)(t0 + 1) * 128 + j] = acc1;
  xdbl[(size_t)(t0 + 2) * 128 + j] = acc2;
  xdbl[(size_t)(t0 + 3) * 128 + j] = acc3;
}

// ---------------- delta = softplus(dt @ dt_proj_w + b)  (fp32) ----------------
__global__ void k_dtproj(const float* __restrict__ xdbl, const float* __restrict__ W,
                         const float* __restrict__ b, float* __restrict__ delta) {
  __shared__ float dt[4][DTR];
  int t0 = blockIdx.x * 4;
  int d = blockIdx.y * 256 + threadIdx.x;
  int tid = threadIdx.x;
  {
    int r = tid >> 6, k = tid & 63;
    dt[r][k] = xdbl[(size_t)(t0 + r) * 128 + k];
  }
  __syncthreads();
  float bias = b[d];
  float acc0 = bias, acc1 = bias, acc2 = bias, acc3 = bias;
#pragma unroll
  for (int k = 0; k < DTR; k++) {
    float w = W[(size_t)k * DI + d];
    acc0 = fmaf(dt[0][k], w, acc0);
    acc1 = fmaf(dt[1][k], w, acc1);
    acc2 = fmaf(dt[2][k], w, acc2);
    acc3 = fmaf(dt[3][k], w, acc3);
  }
  float a[4] = {acc0, acc1, acc2, acc3};
#pragma unroll
  for (int r = 0; r < 4; r++) {
    float v = a[r];
    delta[(size_t)(t0 + r) * DI + d] = (v > 20.f) ? v : log1pf(__expf(v));
  }
}

// ---------------- selective scan (sequential over t) ----------------
// 256 blocks x 128 threads (8 d/block, all CUs busy) + 8-deep register prefetch
// so ~8 steps of dependent compute cover the ~200cy L2 load latency.
#define SPF 8
__global__ void k_scan(const float* __restrict__ delta, const float* __restrict__ xdbl,
                       const float* __restrict__ u, const float* __restrict__ A_log,
                       const float* __restrict__ Dskip, float* __restrict__ y) {
  int n = threadIdx.x & 15, dl = threadIdx.x >> 4;   // dl in 0..7
  int d = blockIdx.x * 8 + dl;
  float An = -__expf(A_log[d * DS + n]);
  float Dd = Dskip[d];
  float h = 0.f;
  float del[SPF], uu[SPF], Bn[SPF], Cn[SPF];
#pragma unroll
  for (int s = 0; s < SPF; s++) {
    del[s] = delta[(size_t)s * DI + d];
    uu[s] = u[(size_t)s * DI + d];
    Bn[s] = xdbl[s * 128 + 64 + n];
    Cn[s] = xdbl[s * 128 + 80 + n];
  }
  for (int t = 0; t < SEQ; t += SPF) {
#pragma unroll
    for (int s = 0; s < SPF; s++) {
      float dA = __expf(del[s] * An);
      h = fmaf(dA, h, del[s] * Bn[s] * uu[s]);
      float p = h * Cn[s];
      p += __shfl_xor(p, 8);
      p += __shfl_xor(p, 4);
      p += __shfl_xor(p, 2);
      p += __shfl_xor(p, 1);
      if (n == 0) y[(size_t)(t + s) * DI + d] = fmaf(uu[s], Dd, p);
      int tn = t + SPF + s;
      if (tn < SEQ) {
        del[s] = delta[(size_t)tn * DI + d];
        uu[s] = u[(size_t)tn * DI + d];
        Bn[s] = xdbl[tn * 128 + 64 + n];
        Cn[s] = xdbl[tn * 128 + 80 + n];
      }
    }
  }
}

// ---------------- y2 = y * silu(res) -> bf16 hi + lo ----------------
__global__ void k_y2(const float* __restrict__ y, const float* __restrict__ xr,
                     u16* __restrict__ hi, u16* __restrict__ lo) {
  int i = blockIdx.x * 256 + threadIdx.x;
  int t = i >> 11, d = i & (DI - 1);
  float r = xr[(size_t)t * (2 * DI) + DI + d];
  float v = y[i] * silu_f(r);
  u16 h = bf16_rn(v);
  hi[i] = h;
  lo[i] = bf16_rn(v - bf16_to_f(h));
}

// ---------------- x += sum of 4 split-K partials ----------------
__global__ void k_add4(float* __restrict__ x, const float* __restrict__ parts) {
  int i = (blockIdx.x * 256 + threadIdx.x) * 4;
  const size_t S = (size_t)SEQ * DM;
  float4 v = *(const float4*)&x[i];
  float4 a = *(const float4*)&parts[i];
  float4 b = *(const float4*)&parts[S + i];
  float4 c = *(const float4*)&parts[2 * S + i];
  float4 d = *(const float4*)&parts[3 * S + i];
  v.x += a.x + b.x + c.x + d.x;
  v.y += a.y + b.y + c.y + d.y;
  v.z += a.z + b.z + c.z + d.z;
  v.w += a.w + b.w + c.w + d.w;
  *(float4*)&x[i] = v;
}

// ---------------- MFMA GEMM: C(M,N) = A(M,K)bf16 @ Bt(N,K) ----------------
#define EPI_STORE 0
#define EPI_ADD 1

__device__ __forceinline__ void async16(const u16* g, u16* l) {
  __builtin_amdgcn_global_load_lds(
      (const __attribute__((address_space(1))) unsigned int*)g,
      (__attribute__((address_space(3))) unsigned int*)l, 16, 0, 0);
}

// XCD-aware bijective swizzle (all grids here are multiples of 8).
__device__ __forceinline__ int xcd_swz(int bx, int nwg) {
  return (bx & 7) * (nwg >> 3) + (bx >> 3);
}

template <int EPI, bool BF32, bool NGUARD>
__launch_bounds__(256)
__global__ void k_gemm(const u16* __restrict__ A, const void* __restrict__ Bt,
                       float* __restrict__ C, int M, int N, int K,
                       int ldA, int ldB, int ldC, int Mb) {
  __shared__ u16 lds_a[128 * 32];
  __shared__ u16 lds_b[128 * 32];
  int bx = xcd_swz(blockIdx.x, gridDim.x);
  int m0 = (bx % Mb) * 128;
  int n0 = (bx / Mb) * 128;
  int tid = threadIdx.x, ln = tid & 63;
  int wv = tid >> 6, wm = wv >> 1, wn = wv & 1;
  int ml = ln & 15, q = ln >> 4;

  f32x4 zero = {0.f, 0.f, 0.f, 0.f};
  f32x4 acc[4][4];
#pragma unroll
  for (int i = 0; i < 4; i++)
#pragma unroll
    for (int j = 0; j < 4; j++) acc[i][j] = zero;

  for (int k0 = 0; k0 < K; k0 += 32) {
    __syncthreads();
#pragma unroll
    for (int r = 0; r < 2; r++) {
      int idx = r * 256 + tid;
      const u16* g = A + (size_t)(m0 + (idx >> 2)) * ldA + k0 + (idx & 3) * 8;
      u16* l = lds_a + (size_t)(r * 256 + (tid & ~63)) * 8;
      async16(g, l);
    }
    if (!BF32) {
#pragma unroll
      for (int r = 0; r < 2; r++) {
        int idx = r * 256 + tid;
        int nr = n0 + (idx >> 2);
        if (NGUARD) nr = min(nr, N - 1);
        const u16* g = (const u16*)Bt + (size_t)nr * ldB + k0 + (idx & 3) * 8;
        u16* l = lds_b + (size_t)(r * 256 + (tid & ~63)) * 8;
        async16(g, l);
      }
    } else {
      // B source fp32 (N,K): read float4, convert to bf16, ds_write
#pragma unroll
      for (int r = 0; r < 4; r++) {
        int idx = r * 256 + tid;
        int row = idx >> 3, cg = idx & 7;
        int nr = n0 + row;
        if (NGUARD) nr = min(nr, N - 1);
        float4 v = *(const float4*)((const float*)Bt + (size_t)nr * ldB + k0 + cg * 4);
        unsigned long long pk =
            (unsigned long long)bf16_rn(v.x) |
            ((unsigned long long)bf16_rn(v.y) << 16) |
            ((unsigned long long)bf16_rn(v.z) << 32) |
            ((unsigned long long)bf16_rn(v.w) << 48);
        *(unsigned long long*)&lds_b[row * 32 + cg * 4] = pk;
      }
    }
    __syncthreads();

    bf16x8 af[4], bfr[4];
#pragma unroll
    for (int i = 0; i < 4; i++)
      af[i] = *(const bf16x8*)&lds_a[(wm * 64 + i * 16 + ml) * 32 + q * 8];
#pragma unroll
    for (int j = 0; j < 4; j++)
      bfr[j] = *(const bf16x8*)&lds_b[(wn * 64 + j * 16 + ml) * 32 + q * 8];
#pragma unroll
    for (int i = 0; i < 4; i++)
#pragma unroll
      for (int j = 0; j < 4; j++)
        acc[i][j] = __builtin_amdgcn_mfma_f32_16x16x32_bf16(af[i], bfr[j], acc[i][j], 0, 0, 0);
  }

  // C/D layout: col=lane&15, row=(lane>>4)*4+reg  [verified m89/m91]
#pragma unroll
  for (int i = 0; i < 4; i++)
#pragma unroll
    for (int j = 0; j < 4; j++) {
      int c = n0 + wn * 64 + j * 16 + ml;
      if (NGUARD && c >= N) continue;
      int rbase = m0 + wm * 64 + i * 16 + q * 4;
#pragma unroll
      for (int rg = 0; rg < 4; rg++) {
        int r = rbase + rg;
        float v = acc[i][j][rg];
        size_t off = (size_t)r * ldC + c;
        if (EPI == EPI_STORE) C[off] = v;
        else C[off] += v;
      }
    }
}

// ---------------- fused split-bf16 GEMM: C = Ah@Bh + Al@Bh + Ah@Bl ----------------
// One staging pass, one C write. Optional split-K via grid z-dim folded into bx:
// sk = bx / (Mb*Nb); K range [sk*kLen, (sk+1)*kLen); C += sk*cStride.
template <int EPI>
__launch_bounds__(256)
__global__ void k_gemm3(const u16* __restrict__ Ah, const u16* __restrict__ Al,
                        const u16* __restrict__ Bh, const u16* __restrict__ Bl,
                        float* __restrict__ C, int ldA, int ldB, int ldC,
                        int Mb, int Nb, int kLen, long long cStride) {
  __shared__ u16 lds_ah[128 * 32];
  __shared__ u16 lds_al[128 * 32];
  __shared__ u16 lds_bh[128 * 32];
  __shared__ u16 lds_bl[128 * 32];
  int bx = xcd_swz(blockIdx.x, gridDim.x);
  int m0 = (bx % Mb) * 128;
  int n0 = ((bx / Mb) % Nb) * 128;
  int sk = bx / (Mb * Nb);
  int k0beg = sk * kLen;
  C += (size_t)sk * cStride;
  int tid = threadIdx.x, ln = tid & 63;
  int wv = tid >> 6, wm = wv >> 1, wn = wv & 1;
  int ml = ln & 15, q = ln >> 4;

  f32x4 zero = {0.f, 0.f, 0.f, 0.f};
  f32x4 acc[4][4];
#pragma unroll
  for (int i = 0; i < 4; i++)
#pragma unroll
    for (int j = 0; j < 4; j++) acc[i][j] = zero;

  for (int k0 = k0beg; k0 < k0beg + kLen; k0 += 32) {
    __syncthreads();
#pragma unroll
    for (int r = 0; r < 2; r++) {
      int idx = r * 256 + tid;
      size_t goffA = (size_t)(m0 + (idx >> 2)) * ldA + k0 + (idx & 3) * 8;
      size_t goffB = (size_t)(n0 + (idx >> 2)) * ldB + k0 + (idx & 3) * 8;
      size_t loff = (size_t)(r * 256 + (tid & ~63)) * 8;
      async16(Ah + goffA, lds_ah + loff);
      async16(Al + goffA, lds_al + loff);
      async16(Bh + goffB, lds_bh + loff);
      async16(Bl + goffB, lds_bl + loff);
    }
    __syncthreads();

    bf16x8 ah[4], al[4], bh[4], bl[4];
#pragma unroll
    for (int i = 0; i < 4; i++) {
      int ro = (wm * 64 + i * 16 + ml) * 32 + q * 8;
      ah[i] = *(const bf16x8*)&lds_ah[ro];
      al[i] = *(const bf16x8*)&lds_al[ro];
    }
#pragma unroll
    for (int j = 0; j < 4; j++) {
      int ro = (wn * 64 + j * 16 + ml) * 32 + q * 8;
      bh[j] = *(const bf16x8*)&lds_bh[ro];
      bl[j] = *(const bf16x8*)&lds_bl[ro];
    }
#pragma unroll
    for (int i = 0; i < 4; i++)
#pragma unroll
      for (int j = 0; j < 4; j++) {
        acc[i][j] = __builtin_amdgcn_mfma_f32_16x16x32_bf16(ah[i], bh[j], acc[i][j], 0, 0, 0);
        acc[i][j] = __builtin_amdgcn_mfma_f32_16x16x32_bf16(al[i], bh[j], acc[i][j], 0, 0, 0);
        acc[i][j] = __builtin_amdgcn_mfma_f32_16x16x32_bf16(ah[i], bl[j], acc[i][j], 0, 0, 0);
      }
  }

#pragma unroll
  for (int i = 0; i < 4; i++)
#pragma unroll
    for (int j = 0; j < 4; j++) {
      int c = n0 + wn * 64 + j * 16 + ml;
      int rbase = m0 + wm * 64 + i * 16 + q * 4;
#pragma unroll
      for (int rg = 0; rg < 4; rg++) {
        int r = rbase + rg;
        float v = acc[i][j][rg];
        size_t off = (size_t)r * ldC + c;
        if (EPI == EPI_STORE) C[off] = v;
        else C[off] += v;
      }
    }
}

// ---------------- host side ----------------
extern "C" void kernel_launch(void* const* d_in, const int* in_sizes, int n_in,
                              void* d_out, int out_size, void* d_ws, size_t ws_size,
                              hipStream_t stream) {
  const int* ids = (const int*)d_in[0];
  const float* E = (const float*)d_in[1];
  const float* norm_scale = (const float*)d_in[2];
  const float* in_proj_w = (const float*)d_in[3];
  const float* conv_w = (const float*)d_in[4];
  const float* conv_b = (const float*)d_in[5];
  const float* x_proj_w = (const float*)d_in[6];
  const float* dt_proj_w = (const float*)d_in[7];
  const float* dt_proj_b = (const float*)d_in[8];
  const float* A_log = (const float*)d_in[9];
  const float* D_skip = (const float*)d_in[10];
  const float* out_proj_w = (const float*)d_in[11];
  const float* norm_f_scale = (const float*)d_in[12];
  float* out = (float*)d_out;

  char* p = (char*)d_ws;
  auto alloc = [&](size_t bytes) { char* r = p; p += (bytes + 255) & ~(size_t)255; return r; };
  float* x = (float*)alloc((size_t)SEQ * DM * 4);
  u16* xn_h = (u16*)alloc((size_t)SEQ * DM * 2);
  u16* xn_l = (u16*)alloc((size_t)SEQ * DM * 2);
  float* xr = (float*)alloc((size_t)SEQ * 2 * DI * 4);
  float* xc = (float*)alloc((size_t)SEQ * DI * 4);
  float* xdbl = (float*)alloc((size_t)SEQ * 128 * 4);
  float* delta = (float*)alloc((size_t)SEQ * DI * 4);
  float* ybuf = (float*)alloc((size_t)SEQ * DI * 4);
  u16* y2h = (u16*)alloc((size_t)SEQ * DI * 2);
  u16* y2l = (u16*)alloc((size_t)SEQ * DI * 2);
  u16* xf_h = (u16*)alloc((size_t)SEQ * DM * 2);
  u16* xf_l = (u16*)alloc((size_t)SEQ * DM * 2);
  float* parts = (float*)alloc((size_t)4 * SEQ * DM * 4);   // split-K partials
  u16 *inTh[NLAY], *inTl[NLAY], *outTh[NLAY], *outTl[NLAY];
  for (int l = 0; l < NLAY; l++) {
    inTh[l] = (u16*)alloc((size_t)(2 * DI) * DM * 2);
    inTl[l] = (u16*)alloc((size_t)(2 * DI) * DM * 2);
    outTh[l] = (u16*)alloc((size_t)DM * DI * 2);
    outTl[l] = (u16*)alloc((size_t)DM * DI * 2);
  }
  // bf16 copy of E (103 MB) if workspace allows; else fall back to in-staging convert.
  size_t ebytes = (size_t)NVOCAB * DM * 2;
  bool useEbf = ((size_t)(p - (char*)d_ws) + ebytes + 256 <= ws_size);
  u16* Ebf = useEbf ? (u16*)alloc(ebytes) : nullptr;

  // weight transposes fp32(R,C) -> bf16 hi/lo (C,R)
  TPack pk;
  int ts = 0;
  for (int l = 0; l < NLAY; l++) {
    pk.d[l * 2 + 0] = {in_proj_w + (size_t)l * DM * 2 * DI, inTh[l], inTl[l], DM, 2 * DI, ts};
    ts += (DM / 32) * (2 * DI / 32);      // 4096
    pk.d[l * 2 + 1] = {out_proj_w + (size_t)l * DI * DM, outTh[l], outTl[l], DI, DM, ts};
    ts += (DI / 32) * (DM / 32);          // 2048
  }
  k_transpose<<<ts, 256, 0, stream>>>(pk);
  if (useEbf)
    k_e2bf<<<(NVOCAB * DM) / (256 * 8), 256, 0, stream>>>(E, Ebf);

  k_embed<<<SEQ, 256, 0, stream>>>(ids, E, x);

  for (int l = 0; l < NLAY; l++) {
    k_rmsnorm<<<SEQ, 256, 0, stream>>>(x, norm_scale + (size_t)l * DM, xn_h, xn_l);
    // xr = Ah*Wh + Al*Wh + Ah*Wl (split-bf16, near-fp32) — single fused pass
    k_gemm3<EPI_STORE><<<8 * 32, 256, 0, stream>>>(
        xn_h, xn_l, inTh[l], inTl[l], xr, DM, DM, 2 * DI, 8, 32, DM, 0);
    k_conv<<<(SEQ * DI) / 256, 256, 0, stream>>>(
        xr, conv_w + (size_t)l * DCONV * DI, conv_b + (size_t)l * DI, xc);
    k_xdbl<<<SEQ / 4, 128, 0, stream>>>(xc, x_proj_w + (size_t)l * DI * 96, xdbl);
    {
      dim3 g(SEQ / 4, DI / 256);
      k_dtproj<<<g, 256, 0, stream>>>(xdbl, dt_proj_w + (size_t)l * DTR * DI,
                                      dt_proj_b + (size_t)l * DI, delta);
    }
    k_scan<<<DI / 8, 128, 0, stream>>>(delta, xdbl, xc,
                                       A_log + (size_t)l * DI * DS,
                                       D_skip + (size_t)l * DI, ybuf);
    k_y2<<<(SEQ * DI) / 256, 256, 0, stream>>>(ybuf, xr, y2h, y2l);
    // out_proj split-K x4: 256 blocks (vs 64), partials then one fused add
    k_gemm3<EPI_STORE><<<8 * 8 * 4, 256, 0, stream>>>(
        y2h, y2l, outTh[l], outTl[l], parts, DI, DI, DM, 8, 8, DI / 4,
        (long long)SEQ * DM);
    k_add4<<<(SEQ * DM) / (4 * 256), 256, 0, stream>>>(x, parts);
  }

  k_rmsnorm<<<SEQ, 256, 0, stream>>>(x, norm_f_scale, xf_h, xf_l);
  int nblk = (NVOCAB + 127) / 128;  // 393
  if (useEbf) {
    // pure global_load_lds bf16 path (m97 structure)
    k_gemm<EPI_STORE, false, true><<<8 * nblk, 256, 0, stream>>>(
        xf_h, Ebf, out, SEQ, NVOCAB, DM, DM, DM, NVOCAB, 8);
  } else {
    k_gemm<EPI_STORE, true, true><<<8 * nblk, 256, 0, stream>>>(
        xf_h, E, out, SEQ, NVOCAB, DM, DM, DM, NVOCAB, 8);
  }
}